// Round 8
// baseline (831.797 us; speedup 1.0000x reference)
//
#include <hip/hip_runtime.h>
#include <stdint.h>

typedef unsigned int u32;
typedef unsigned long long u64;

#define HH 256
#define WW 512
#define HW (HH*WW)          // 131072
#define N2 (2*HW)           // 262144 per branch
#define NT (2*N2)           // 524288 total boxes
#define TOPK 4096
#define SCORE_THR 0.2f
#define NMS_THR 0.15f
#define NBIN 32768          // 15-bit histogram of key>>17

// ---- workspace layout (bytes) ----
// [0, 2MB)          keys  -> reused as NMS mask (4096*64 u64 = 2 MB exactly)
// [2MB, 2MB+128K)   ghist -> reused: cand (64K) at +0, stand (64K) at +64K
//                   (ghist dead after k_select phase 1; cand dead after k_rank,
//                    stand born in k_boxes which runs after k_rank)
#define OFF_KEYS   0ull
#define OFF_GHIST  ((size_t)NT*4)                  // 2,097,152  (128 KB)
#define OFF_CAND   OFF_GHIST                       // u64[8192] = 64 KB
#define OFF_STAND  (OFF_GHIST + 65536)             // float4[4096] = 64 KB
#define OFF_CNT    (OFF_GHIST + 131072)            // u32 (+pad 16)
#define OFF_SELIDX (OFF_CNT + 16)                  // u32[4096]
#define OFF_SELSC  (OFF_SELIDX + (size_t)TOPK*4)   // f32[4096]
// end = 2,261,008 bytes  (< 2,263,216 used by the passing R6 layout)

// orderable key for float (descending sortable as unsigned)
__device__ __forceinline__ u32 f2ord(float f) {
    u32 b = __float_as_uint(f);
    return (b & 0x80000000u) ? ~b : (b | 0x80000000u);
}

// ---------------- K1: scores -> keys + global 15-bit histogram -------------
// Valid keys (s > thr) occupy few hot bins but each holds only ~2k entries,
// and adds are spread across 512 blocks -> global atomics are cheap. key==0
// (masked) is skipped: 220k same-address adds would serialize.
__global__ void __launch_bounds__(1024) k_keys(const float* __restrict__ psm_v,
                                               const float* __restrict__ psm_i,
                                               u32* __restrict__ keys,
                                               u32* __restrict__ ghist) {
    int n = blockIdx.x * 1024 + threadIdx.x;
    int br = n >> 18;
    int m  = n & (N2 - 1);
    int a  = m & 1;
    int hw = m >> 1;
    const float* psm = br ? psm_i : psm_v;
    float x = psm[a * HW + hw];
    float s = 1.0f / (1.0f + __builtin_expf(-x));   // mirror ref f32 sigmoid
    u32 key = 0u;
    if (s > SCORE_THR) key = f2ord(s);
    keys[n] = key;
    if (key) atomicAdd(&ghist[key >> 17], 1u);
}

// ---------------- K2: single-block cut-find + compact ----------------------
// Finds C = largest bin with suffix(C) >= TOPK (so TOPK <= count <= TOPK +
// cut-bin population ~2.2k < 8192), then compacts keys with bin >= C.
// Exact ordering is k_rank's job, so cand order / slack are irrelevant.
__global__ void __launch_bounds__(1024) k_select(const u32* __restrict__ ghist,
                                                 const u32* __restrict__ keys,
                                                 u64* __restrict__ cand,
                                                 u32* __restrict__ cnt) {
    __shared__ u32 part[1024];
    __shared__ u32 cut_sh, cnt_sh;
    int tid = threadIdx.x;
    // phase 1a: per-thread partial sum over 32 bins (8 x uint4)
    const uint4* g4 = (const uint4*)ghist;
    u32 s = 0;
#pragma unroll
    for (int j = 0; j < 8; ++j) {
        uint4 h = g4[tid * 8 + j];
        s += h.x + h.y + h.z + h.w;
    }
    part[tid] = s;
    if (tid == 0) { cut_sh = 1u; cnt_sh = 0u; }
    __syncthreads();
    // phase 1b: wave 0 suffix-scans the 1024 partials, finds boundary bin
    if (tid < 64) {
        int l = tid;
        u32 h[16], loc[16];
#pragma unroll
        for (int j = 0; j < 16; ++j) h[j] = part[l * 16 + j];
        loc[15] = h[15];
#pragma unroll
        for (int j = 14; j >= 0; --j) loc[j] = loc[j + 1] + h[j];
        u32 T = loc[0];
        u32 incl = T;                          // inclusive suffix scan over lanes
#pragma unroll
        for (int d = 1; d < 64; d <<= 1) {
            u32 v = __shfl_down(incl, d);
            if (l + d < 64) incl += v;
        }
        u32 E = incl - T;                      // sum over lanes > l
        int pstar = -1; u32 snext = 0;
#pragma unroll
        for (int j = 0; j < 16; ++j) {
            u32 S  = loc[j] + E;
            u32 Sn = (j < 15 ? loc[j + 1] : 0u) + E;
            if (S >= (u32)TOPK && Sn < (u32)TOPK) { pstar = l * 16 + j; snext = Sn; }
        }
        u64 bal = __ballot(pstar >= 0);        // exactly one lane (if total>=TOPK)
        if (bal) {
            int src = (int)__builtin_ctzll(bal);
            int p   = __shfl(pstar, src);
            u32 sn  = __shfl(snext, src);
            u32 hb  = (l < 32) ? ghist[p * 32 + l] : 0u;   // bin p*32+l
            u32 acc = sn;
            int cbin = p * 32;
            for (int j = 31; j >= 0; --j) {    // uniform walk, readlane broadcast
                acc += (u32)__builtin_amdgcn_readlane((int)hb, j);
                if (acc >= (u32)TOPK) { cbin = p * 32 + j; break; }
            }
            if (l == 0) cut_sh = (u32)cbin;    // single designated writer
        }
    }
    __syncthreads();
    u32 C = cut_sh;
    // phase 2: compact (key==0 auto-excluded since C >= 1 and 0>>17 == 0)
    const uint4* k4 = (const uint4*)keys;
    for (int i = 0; i < NT / 4096; ++i) {
        uint4 k = k4[i * 1024 + tid];
        int base = i * 4096 + tid * 4;
        u32 kk[4] = {k.x, k.y, k.z, k.w};
#pragma unroll
        for (int j = 0; j < 4; ++j) {
            if ((kk[j] >> 17) >= C) {
                u32 pos = atomicAdd(&cnt_sh, 1u);
                if (pos < 8192u)
                    cand[pos] = ((u64)kk[j] << 32) | (u64)(u32)(~(u32)(base + j));
            }
        }
    }
    __syncthreads();
    if (tid == 0) *cnt = (cnt_sh > 8192u) ? 8192u : cnt_sh;
}

// ---------------- K3: rank-by-counting selection ----------------------------
// Keys distinct (index embedded) => rank is an exact permutation; rank<TOPK
// reproduces the reference's descending order exactly, independent of cand order.
__global__ void __launch_bounds__(256) k_rank(const u64* __restrict__ cand,
                                              const u32* __restrict__ cnt,
                                              u32* __restrict__ sel_idx) {
    __shared__ u64 tile[1024];
    int tid = threadIdx.x;
    int i = blockIdx.x * 256 + tid;
    u32 c = *cnt;
    if (c > 8192u) c = 8192u;
    u64 my = (i < (int)c) ? cand[i] : 0ull;
    u32 rank = 0;
    for (u32 base = 0; base < c; base += 1024) {
#pragma unroll
        for (int k = 0; k < 4; ++k) {
            u32 idx = base + tid + k * 256;
            tile[tid + k * 256] = (idx < c) ? cand[idx] : 0ull;
        }
        __syncthreads();
        u32 lim = (c - base < 1024u) ? (c - base) : 1024u;
#pragma unroll 4
        for (u32 k = 0; k < lim; ++k) rank += (tile[k] > my) ? 1u : 0u;
        __syncthreads();
    }
    if (i < (int)c && rank < (u32)TOPK)
        sel_idx[rank] = ~((u32)(my & 0xFFFFFFFFull));
}

// ---------------- box math helpers (mirror the jax reference) ---------------
__device__ __forceinline__ void box_corners(const float b[7], float cx[8], float cy[8], float cz[8]) {
    const float sx[8] = {0.5f,0.5f,-0.5f,-0.5f,0.5f,0.5f,-0.5f,-0.5f};
    const float sy[8] = {0.5f,-0.5f,-0.5f,0.5f,0.5f,-0.5f,-0.5f,0.5f};
    const float sz[8] = {-0.5f,-0.5f,-0.5f,-0.5f,0.5f,0.5f,0.5f,0.5f};
    float c = __builtin_cosf(b[6]), s = __builtin_sinf(b[6]);
#pragma unroll
    for (int k = 0; k < 8; k++) {
        float x = b[5] * sx[k], y = b[4] * sy[k], z = b[3] * sz[k];
        cx[k] = x * c - y * s + b[0];
        cy[k] = x * s + y * c + b[1];
        cz[k] = z + b[2];
    }
}

__device__ __forceinline__ void proj_T(const float* __restrict__ T, float cx[8], float cy[8], float cz[8]) {
#pragma unroll
    for (int k = 0; k < 8; k++) {
        float x = cx[k], y = cy[k], z = cz[k];
        cx[k] = T[0] * x + T[1] * y + T[2]  * z + T[3];
        cy[k] = T[4] * x + T[5] * y + T[6]  * z + T[7];
        cz[k] = T[8] * x + T[9] * y + T[10] * z + T[11];
    }
}

__device__ __forceinline__ void corner_to_center(const float cx[8], const float cy[8], const float cz[8], float b[7]) {
    float mx = 0.f, my = 0.f, mz = 0.f;
#pragma unroll
    for (int k = 0; k < 8; k++) { mx += cx[k]; my += cy[k]; mz += cz[k]; }
    mx *= 0.125f; my *= 0.125f; mz *= 0.125f;
    float htop = (cz[4] + cz[5] + cz[6] + cz[7]) * 0.25f;
    float hbot = (cz[0] + cz[1] + cz[2] + cz[3]) * 0.25f;
    const int lA[4] = {0,1,4,5}, lB[4] = {3,2,7,6};
    const int wA[4] = {0,3,4,7}, wB[4] = {1,2,5,6};
    float l = 0.f, w = 0.f, dx = 0.f, dy = 0.f;
#pragma unroll
    for (int i = 0; i < 4; i++) {
        float ax = cx[lA[i]] - cx[lB[i]];
        float ay = cy[lA[i]] - cy[lB[i]];
        l += __builtin_sqrtf(ax * ax + ay * ay);
        dx += ax; dy += ay;
    }
#pragma unroll
    for (int i = 0; i < 4; i++) {
        float ax = cx[wA[i]] - cx[wB[i]];
        float ay = cy[wA[i]] - cy[wB[i]];
        w += __builtin_sqrtf(ax * ax + ay * ay);
    }
    b[0] = mx; b[1] = my; b[2] = mz;
    b[3] = htop - hbot;
    b[4] = w * 0.25f;
    b[5] = l * 0.25f;
    b[6] = atan2f(dy, dx);
}

// ---------------- K4: decode selected boxes -> out corners + standup --------
__global__ void __launch_bounds__(256) k_boxes(const float* __restrict__ anchors,
                                               const float* __restrict__ psm_v,
                                               const float* __restrict__ psm_i,
                                               const float* __restrict__ rm_v,
                                               const float* __restrict__ rm_i,
                                               const float* __restrict__ tproj,
                                               const float* __restrict__ tego,
                                               const u32* __restrict__ sel_idx,
                                               float* __restrict__ sel_sc,
                                               float* __restrict__ out,
                                               float4* __restrict__ stand) {
    int k = blockIdx.x * blockDim.x + threadIdx.x;
    if (k >= TOPK) return;
    int n = (int)(sel_idx[k] & (u32)(NT - 1));
    int br = n >> 18;
    int m  = n & (N2 - 1);
    int a  = m & 1;
    int hw = m >> 1;

    const float* psm = br ? psm_i : psm_v;
    float xs = psm[a * HW + hw];
    float s  = 1.0f / (1.0f + __builtin_expf(-xs));
    sel_sc[k] = (s > SCORE_THR) ? s : -1.0f;

    const float* rm = br ? rm_i : rm_v;
    float d[7];
#pragma unroll
    for (int j = 0; j < 7; j++) d[j] = rm[(a * 7 + j) * HW + hw];
    const float* anc = anchors + (size_t)m * 7;
    float a0 = anc[0], a1 = anc[1], a2 = anc[2], a3 = anc[3], a4 = anc[4], a5 = anc[5], a6 = anc[6];
    float ad = __builtin_sqrtf(a4 * a4 + a5 * a5);
    float b[7];
    b[0] = d[0] * ad + a0;
    b[1] = d[1] * ad + a1;
    b[2] = d[2] * a3 + a2;
    b[3] = __builtin_expf(d[3]) * a3;
    b[4] = __builtin_expf(d[4]) * a4;
    b[5] = __builtin_expf(d[5]) * a5;
    b[6] = d[6] + a6;

    if (br) {  // infrared branch: corners -> t_proj -> back to center form
        float cx[8], cy[8], cz[8];
        box_corners(b, cx, cy, cz);
        proj_T(tproj, cx, cy, cz);
        corner_to_center(cx, cy, cz, b);
    }

    float cx[8], cy[8], cz[8];
    box_corners(b, cx, cy, cz);
    proj_T(tego, cx, cy, cz);

    float mnx = cx[0], mny = cy[0], mxx = cx[0], mxy = cy[0];
#pragma unroll
    for (int c = 0; c < 8; c++) {
        out[(size_t)k * 25 + c * 3 + 0] = cx[c];
        out[(size_t)k * 25 + c * 3 + 1] = cy[c];
        out[(size_t)k * 25 + c * 3 + 2] = cz[c];
        mnx = fminf(mnx, cx[c]); mny = fminf(mny, cy[c]);
        mxx = fmaxf(mxx, cx[c]); mxy = fmaxf(mxy, cy[c]);
    }
    stand[k] = make_float4(mnx, mny, mxx, mxy);
}

// ---------------- K5: suppression bitmask (4 rows per 256-thr block) --------
// Each wave handles one row i; __ballot is per-wave so semantics match the
// old 64-thread version; 4 rows share the stand[] stream via L1.
__global__ void __launch_bounds__(256) k_mask(const float4* __restrict__ stand,
                                              u64* __restrict__ mask) {
    int i = blockIdx.x * 4 + (threadIdx.x >> 6);
    int t = threadIdx.x & 63;
    int w0 = i >> 6;                    // chunks below diagonal are all-zero
    float4 bi = stand[i];
    float areai = (bi.z - bi.x) * (bi.w - bi.y);
    u64 myword = 0ull;
    for (int w = w0; w < 64; ++w) {
        int j = w * 64 + t;
        float4 bj = stand[j];
        float areaj = (bj.z - bj.x) * (bj.w - bj.y);
        float ltx = fmaxf(bi.x, bj.x), lty = fmaxf(bi.y, bj.y);
        float rbx = fminf(bi.z, bj.z), rby = fminf(bi.w, bj.w);
        float iw = fmaxf(rbx - ltx, 0.0f), ih = fmaxf(rby - lty, 0.0f);
        float inter = iw * ih;
        float iou = inter / (areai + areaj - inter + 1e-6f);
        bool sup = (iou > NMS_THR) && (j > i);
        u64 bits = __ballot(sup);
        if (t == w) myword = bits;
    }
    mask[(size_t)i * 64 + t] = myword;
}

// ---------------- K6: 4-wave cooperative greedy NMS (scalar chain + dbuf) ---
// Chain is fully scalar (readfirstlane on curw -> alive/kb live in SGPRs;
// ~6 SALU + 2 readlane per kept box). Row-words double-buffered in registers:
// chunk B+1's loads fly during chunk B's chain+fold, hiding HBM latency.
__device__ __forceinline__ void nms_step(int B, u64 (&rcur)[16], u64 (&rnxt)[16],
                                         const u64* __restrict__ mask,
                                         const float* __restrict__ sc,
                                         u64& colB, float& mysc,
                                         u64* remv_sh, u64* keep_sh, u64* kb_sh,
                                         int w, int l) {
    if (B + 1 < 64) {   // prefetch next chunk's rows (chain-independent)
        const u64* rp = mask + (size_t)((B + 1) * 64 + w * 16) * 64 + l;
#pragma unroll
        for (int k2 = 0; k2 < 16; ++k2) rnxt[k2] = rp[(size_t)k2 * 64];
    }
    u64 colB_next = 0ull;
    float sc_next = 0.0f;
    if (w == 0) {
        if (B + 1 < 64) {
            colB_next = mask[(size_t)((B + 1) * 64 + l) * 64 + (B + 1)];
            sc_next   = sc[(B + 1) * 64 + l];
        }
        u64 validm = __ballot(mysc > SCORE_THR);            // SGPR
        u64 c0 = remv_sh[B];
        u64 curw = (((u64)(u32)__builtin_amdgcn_readfirstlane((int)(u32)(c0 >> 32))) << 32)
                 |  ((u64)(u32)__builtin_amdgcn_readfirstlane((int)(u32)c0));
        u32 clo = (u32)colB, chi = (u32)(colB >> 32);
        u64 alive = validm & ~curw;                          // SGPR chain
        u64 kb = 0ull;
        while (alive) {
            int r = (int)__builtin_ctzll(alive);             // s_ff1
            u64 col_r = (((u64)(u32)__builtin_amdgcn_readlane((int)chi, r)) << 32)
                      |   (u64)(u32)__builtin_amdgcn_readlane((int)clo, r);
            kb |= 1ull << r;
            alive &= ~(col_r | (1ull << r));
        }
        if (l == 0) { *kb_sh = kb; keep_sh[B] = kb; }
    }
    __syncthreads();     // kb visible; remv_sh[B] read precedes fold writes
    u64 kb = *kb_sh;
    u64 p = 0ull;
#pragma unroll
    for (int k2 = 0; k2 < 16; ++k2)
        p |= rcur[k2] & (0ull - ((kb >> (w * 16 + k2)) & 1ull));
    if (p) atomicOr(&remv_sh[l], p);
    __syncthreads();     // fold(B) complete before chain reads remv_sh[B+1]
    colB = colB_next;
    mysc = sc_next;
}

__global__ void __launch_bounds__(256) k_nms(const u64* __restrict__ mask,
                                             const float* __restrict__ sc,
                                             float* __restrict__ out) {
    __shared__ u64 remv_sh[64];
    __shared__ u64 keep_sh[64];
    __shared__ u64 kb_sh;
    int tid = threadIdx.x;
    int w = tid >> 6, l = tid & 63;
    if (tid < 64) remv_sh[tid] = 0ull;
    u64 bufA[16], bufB[16];
    {   // preload chunk 0 rows
        const u64* rp = mask + (size_t)(w * 16) * 64 + l;
#pragma unroll
        for (int k2 = 0; k2 < 16; ++k2) bufA[k2] = rp[(size_t)k2 * 64];
    }
    u64 colB = 0ull;
    float mysc = 0.0f;
    if (w == 0) { colB = mask[(size_t)l * 64]; mysc = sc[l]; }
    __syncthreads();
    for (int B = 0; B < 64; B += 2) {
        nms_step(B,     bufA, bufB, mask, sc, colB, mysc, remv_sh, keep_sh, &kb_sh, w, l);
        nms_step(B + 1, bufB, bufA, mask, sc, colB, mysc, remv_sh, keep_sh, &kb_sh, w, l);
    }
#pragma unroll
    for (int j = 0; j < 16; ++j) {
        int i = tid * 16 + j;
        float s = sc[i];
        out[(size_t)i * 25 + 24] = ((keep_sh[i >> 6] >> (i & 63)) & 1ull) ? s : 0.0f;
    }
}

extern "C" void kernel_launch(void* const* d_in, const int* in_sizes, int n_in,
                              void* d_out, int out_size, void* d_ws, size_t ws_size,
                              hipStream_t stream) {
    const float* anchors = (const float*)d_in[0];
    const float* psm_v   = (const float*)d_in[1];
    const float* rm_v    = (const float*)d_in[2];
    const float* psm_i   = (const float*)d_in[3];
    const float* rm_i    = (const float*)d_in[4];
    const float* tproj   = (const float*)d_in[5];
    const float* tego    = (const float*)d_in[6];
    float* out = (float*)d_out;
    char* ws = (char*)d_ws;

    u32*    keys    = (u32*)(ws + OFF_KEYS);
    u64*    mask    = (u64*)(ws + OFF_KEYS);    // reuse after keys consumed
    u32*    ghist   = (u32*)(ws + OFF_GHIST);
    u64*    cand    = (u64*)(ws + OFF_CAND);    // inside dead ghist region
    float4* stand   = (float4*)(ws + OFF_STAND);// inside dead ghist region
    u32*    cnt     = (u32*)(ws + OFF_CNT);
    u32*    sel_idx = (u32*)(ws + OFF_SELIDX);
    float*  sel_sc  = (float*)(ws + OFF_SELSC);

    hipMemsetAsync(ws + OFF_GHIST, 0, NBIN * 4, stream);
    k_keys   <<<NT / 1024, 1024, 0, stream>>>(psm_v, psm_i, keys, ghist);
    k_select <<<1, 1024, 0, stream>>>(ghist, keys, cand, cnt);
    k_rank   <<<32, 256, 0, stream>>>(cand, cnt, sel_idx);
    k_boxes  <<<TOPK / 256, 256, 0, stream>>>(anchors, psm_v, psm_i, rm_v, rm_i,
                                              tproj, tego, sel_idx, sel_sc, out, stand);
    k_mask   <<<TOPK / 4, 256, 0, stream>>>(stand, mask);
    k_nms    <<<1, 256, 0, stream>>>(mask, sel_sc, out);
}

// Round 9
// 421.776 us; speedup vs baseline: 1.9721x; 1.9721x over previous
//
#include <hip/hip_runtime.h>
#include <stdint.h>

typedef unsigned int u32;
typedef unsigned long long u64;

#define HH 256
#define WW 512
#define HW (HH*WW)          // 131072
#define N2 (2*HW)           // 262144 per branch
#define NT (2*N2)           // 524288 total boxes
#define TOPK 4096
#define SCORE_THR 0.2f
#define NMS_THR 0.15f

// ---- workspace layout (bytes) ----
// [0, 2MB)  keys -> reused as NMS mask (4096*64 u64 = 2 MB exactly)
#define OFF_KEYS   0ull
#define OFF_GHIST  ((size_t)NT*4)                  // u32[1024] = 4 KB
#define OFF_CAND   (OFF_GHIST + 4096)              // u64[8192] = 64 KB
#define OFF_STAND  (OFF_CAND + 65536)              // float4[4096] = 64 KB
#define OFF_CNT    (OFF_STAND + 65536)             // u32 (+pad 16)
#define OFF_SELIDX (OFF_CNT + 16)                  // u32[4096]
#define OFF_SELSC  (OFF_SELIDX + (size_t)TOPK*4)   // f32[4096]

// orderable key for float (descending sortable as unsigned)
__device__ __forceinline__ u32 f2ord(float f) {
    u32 b = __float_as_uint(f);
    return (b & 0x80000000u) ? ~b : (b | 0x80000000u);
}

// ---------------- K1: scores -> keys + per-block LDS hist1 -> global -------
// R1's proven structure: LDS histogram per block, then <=1024 global adds per
// block (only ~190 non-zero bins). Skips key==0 (8% masked keys).
__global__ void __launch_bounds__(1024) k_keys(const float* __restrict__ psm_v,
                                               const float* __restrict__ psm_i,
                                               u32* __restrict__ keys,
                                               u32* __restrict__ ghist) {
    __shared__ u32 lh[1024];
    int t = threadIdx.x;
    lh[t] = 0;
    __syncthreads();
    int n = blockIdx.x * 1024 + t;
    int br = n >> 18;
    int m  = n & (N2 - 1);
    int a  = m & 1;
    int hw = m >> 1;
    const float* psm = br ? psm_i : psm_v;
    float x = psm[a * HW + hw];
    float s = 1.0f / (1.0f + __builtin_expf(-x));   // mirror ref f32 sigmoid
    u32 key = 0u;
    if (s > SCORE_THR) key = f2ord(s);
    keys[n] = key;
    if (key) atomicAdd(&lh[key >> 22], 1u);
    __syncthreads();
    u32 c = lh[t];
    if (c) atomicAdd(&ghist[t], c);
}

// Wave-0 suffix-scan pivot over a 1024-entry count array (16 entries/lane).
// suffix(b) = #keys with bin >= b is non-increasing -> unique crossing lane
// writes the result directly (race-free winner-writes, R1 pattern).
__device__ __forceinline__ void pivot1024(const u32* __restrict__ arr, u32 target,
                                          u32* out_bin, u32* out_next, int l) {
    u32 h[16], loc[16];
#pragma unroll
    for (int j = 0; j < 16; ++j) h[j] = arr[l * 16 + j];
    loc[15] = h[15];
#pragma unroll
    for (int j = 14; j >= 0; --j) loc[j] = loc[j + 1] + h[j];
    u32 T = loc[0];
    u32 incl = T;                          // inclusive suffix scan over lanes
#pragma unroll
    for (int d = 1; d < 64; d <<= 1) {
        u32 v = __shfl_down(incl, d);
        if (l + d < 64) incl += v;
    }
    u32 E = incl - T;                      // sum over lanes > l
#pragma unroll
    for (int j = 0; j < 16; ++j) {
        u32 S  = loc[j] + E;                           // suffix(l*16+j)
        u32 Sn = (j < 15 ? loc[j + 1] : 0u) + E;       // suffix(l*16+j+1)
        if (S >= target && Sn < target) {              // exactly one (lane,j)
            *out_bin = (u32)(l * 16 + j);
            *out_next = Sn;
        }
    }
}

// ---------------- K2: pivot1 -> hist2 -> pivot2 -> compact (1 block) -------
__global__ void __launch_bounds__(1024) k_select(const u32* __restrict__ ghist,
                                                 const u32* __restrict__ keys,
                                                 u64* __restrict__ cand,
                                                 u32* __restrict__ cnt) {
    __shared__ u32 lh[1024];
    __shared__ u32 b1_sh, t2_sh, b2_sh, cnt_sh;
    int tid = threadIdx.x;
    lh[tid] = ghist[tid];
    if (tid == 0) cnt_sh = 0u;
    __syncthreads();
    // pivot 1: 10-bit bin b1, residual target inside it
    if (tid < 64) {
        u32 b = 0, sn = 0, got = 0;
        // winner lane sets got via out-params trick: use locals then write
        u32 bin = 0xFFFFFFFFu, nxt = 0;
        pivot1024(lh, (u32)TOPK, &bin, &nxt, tid);
        if (bin != 0xFFFFFFFFu) { b1_sh = bin; t2_sh = (u32)TOPK - nxt; }
        (void)b; (void)sn; (void)got;
    }
    __syncthreads();
    u32 b1 = b1_sh;
    u32 target2 = t2_sh;
    lh[tid] = 0;
    __syncthreads();
    // hist2: key>>12 (next 10 bits) within bin b1
    const uint4* k4 = (const uint4*)keys;
    for (int i = 0; i < NT / 4096; ++i) {
        uint4 k = k4[i * 1024 + tid];
        if ((k.x >> 22) == b1) atomicAdd(&lh[(k.x >> 12) & 1023u], 1u);
        if ((k.y >> 22) == b1) atomicAdd(&lh[(k.y >> 12) & 1023u], 1u);
        if ((k.z >> 22) == b1) atomicAdd(&lh[(k.z >> 12) & 1023u], 1u);
        if ((k.w >> 22) == b1) atomicAdd(&lh[(k.w >> 12) & 1023u], 1u);
    }
    __syncthreads();
    // pivot 2 (winner-writes)
    if (tid < 64) {
        u32 bin = 0xFFFFFFFFu, nxt = 0;
        pivot1024(lh, target2, &bin, &nxt, tid);
        if (bin != 0xFFFFFFFFu) b2_sh = bin;
    }
    __syncthreads();
    u32 thr20 = (b1 << 10) | b2_sh;
    // compact: keys with (key>>12) >= thr20  (count in [TOPK, TOPK+~100])
    for (int i = 0; i < NT / 4096; ++i) {
        uint4 k = k4[i * 1024 + tid];
        int base = i * 4096 + tid * 4;
        u32 kk[4] = {k.x, k.y, k.z, k.w};
#pragma unroll
        for (int j = 0; j < 4; ++j) {
            if ((kk[j] >> 12) >= thr20) {
                u32 pos = atomicAdd(&cnt_sh, 1u);
                if (pos < 8192u)
                    cand[pos] = ((u64)kk[j] << 32) | (u64)(u32)(~(u32)(base + j));
            }
        }
    }
    __syncthreads();
    if (tid == 0) *cnt = (cnt_sh > 8192u) ? 8192u : cnt_sh;
}

// ---------------- K3: rank-by-counting selection ----------------------------
// Keys distinct (index embedded) => rank is an exact permutation; rank<TOPK
// reproduces the reference's descending order exactly.
__global__ void __launch_bounds__(256) k_rank(const u64* __restrict__ cand,
                                              const u32* __restrict__ cnt,
                                              u32* __restrict__ sel_idx) {
    __shared__ u64 tile[1024];
    int tid = threadIdx.x;
    int i = blockIdx.x * 256 + tid;
    u32 c = *cnt;
    if (c > 8192u) c = 8192u;
    u64 my = (i < (int)c) ? cand[i] : 0ull;
    u32 rank = 0;
    for (u32 base = 0; base < c; base += 1024) {
#pragma unroll
        for (int k = 0; k < 4; ++k) {
            u32 idx = base + tid + k * 256;
            tile[tid + k * 256] = (idx < c) ? cand[idx] : 0ull;
        }
        __syncthreads();
        u32 lim = (c - base < 1024u) ? (c - base) : 1024u;
#pragma unroll 4
        for (u32 k = 0; k < lim; ++k) rank += (tile[k] > my) ? 1u : 0u;
        __syncthreads();
    }
    if (i < (int)c && rank < (u32)TOPK)
        sel_idx[rank] = ~((u32)(my & 0xFFFFFFFFull));
}

// ---------------- box math helpers (mirror the jax reference) ---------------
__device__ __forceinline__ void box_corners(const float b[7], float cx[8], float cy[8], float cz[8]) {
    const float sx[8] = {0.5f,0.5f,-0.5f,-0.5f,0.5f,0.5f,-0.5f,-0.5f};
    const float sy[8] = {0.5f,-0.5f,-0.5f,0.5f,0.5f,-0.5f,-0.5f,0.5f};
    const float sz[8] = {-0.5f,-0.5f,-0.5f,-0.5f,0.5f,0.5f,0.5f,0.5f};
    float c = __builtin_cosf(b[6]), s = __builtin_sinf(b[6]);
#pragma unroll
    for (int k = 0; k < 8; k++) {
        float x = b[5] * sx[k], y = b[4] * sy[k], z = b[3] * sz[k];
        cx[k] = x * c - y * s + b[0];
        cy[k] = x * s + y * c + b[1];
        cz[k] = z + b[2];
    }
}

__device__ __forceinline__ void proj_T(const float* __restrict__ T, float cx[8], float cy[8], float cz[8]) {
#pragma unroll
    for (int k = 0; k < 8; k++) {
        float x = cx[k], y = cy[k], z = cz[k];
        cx[k] = T[0] * x + T[1] * y + T[2]  * z + T[3];
        cy[k] = T[4] * x + T[5] * y + T[6]  * z + T[7];
        cz[k] = T[8] * x + T[9] * y + T[10] * z + T[11];
    }
}

__device__ __forceinline__ void corner_to_center(const float cx[8], const float cy[8], const float cz[8], float b[7]) {
    float mx = 0.f, my = 0.f, mz = 0.f;
#pragma unroll
    for (int k = 0; k < 8; k++) { mx += cx[k]; my += cy[k]; mz += cz[k]; }
    mx *= 0.125f; my *= 0.125f; mz *= 0.125f;
    float htop = (cz[4] + cz[5] + cz[6] + cz[7]) * 0.25f;
    float hbot = (cz[0] + cz[1] + cz[2] + cz[3]) * 0.25f;
    const int lA[4] = {0,1,4,5}, lB[4] = {3,2,7,6};
    const int wA[4] = {0,3,4,7}, wB[4] = {1,2,5,6};
    float l = 0.f, w = 0.f, dx = 0.f, dy = 0.f;
#pragma unroll
    for (int i = 0; i < 4; i++) {
        float ax = cx[lA[i]] - cx[lB[i]];
        float ay = cy[lA[i]] - cy[lB[i]];
        l += __builtin_sqrtf(ax * ax + ay * ay);
        dx += ax; dy += ay;
    }
#pragma unroll
    for (int i = 0; i < 4; i++) {
        float ax = cx[wA[i]] - cx[wB[i]];
        float ay = cy[wA[i]] - cy[wB[i]];
        w += __builtin_sqrtf(ax * ax + ay * ay);
    }
    b[0] = mx; b[1] = my; b[2] = mz;
    b[3] = htop - hbot;
    b[4] = w * 0.25f;
    b[5] = l * 0.25f;
    b[6] = atan2f(dy, dx);
}

// ---------------- K4: decode selected boxes -> out corners + standup --------
__global__ void __launch_bounds__(256) k_boxes(const float* __restrict__ anchors,
                                               const float* __restrict__ psm_v,
                                               const float* __restrict__ psm_i,
                                               const float* __restrict__ rm_v,
                                               const float* __restrict__ rm_i,
                                               const float* __restrict__ tproj,
                                               const float* __restrict__ tego,
                                               const u32* __restrict__ sel_idx,
                                               float* __restrict__ sel_sc,
                                               float* __restrict__ out,
                                               float4* __restrict__ stand) {
    int k = blockIdx.x * blockDim.x + threadIdx.x;
    if (k >= TOPK) return;
    int n = (int)(sel_idx[k] & (u32)(NT - 1));
    int br = n >> 18;
    int m  = n & (N2 - 1);
    int a  = m & 1;
    int hw = m >> 1;

    const float* psm = br ? psm_i : psm_v;
    float xs = psm[a * HW + hw];
    float s  = 1.0f / (1.0f + __builtin_expf(-xs));
    sel_sc[k] = (s > SCORE_THR) ? s : -1.0f;

    const float* rm = br ? rm_i : rm_v;
    float d[7];
#pragma unroll
    for (int j = 0; j < 7; j++) d[j] = rm[(a * 7 + j) * HW + hw];
    const float* anc = anchors + (size_t)m * 7;
    float a0 = anc[0], a1 = anc[1], a2 = anc[2], a3 = anc[3], a4 = anc[4], a5 = anc[5], a6 = anc[6];
    float ad = __builtin_sqrtf(a4 * a4 + a5 * a5);
    float b[7];
    b[0] = d[0] * ad + a0;
    b[1] = d[1] * ad + a1;
    b[2] = d[2] * a3 + a2;
    b[3] = __builtin_expf(d[3]) * a3;
    b[4] = __builtin_expf(d[4]) * a4;
    b[5] = __builtin_expf(d[5]) * a5;
    b[6] = d[6] + a6;

    if (br) {  // infrared branch: corners -> t_proj -> back to center form
        float cx[8], cy[8], cz[8];
        box_corners(b, cx, cy, cz);
        proj_T(tproj, cx, cy, cz);
        corner_to_center(cx, cy, cz, b);
    }

    float cx[8], cy[8], cz[8];
    box_corners(b, cx, cy, cz);
    proj_T(tego, cx, cy, cz);

    float mnx = cx[0], mny = cy[0], mxx = cx[0], mxy = cy[0];
#pragma unroll
    for (int c = 0; c < 8; c++) {
        out[(size_t)k * 25 + c * 3 + 0] = cx[c];
        out[(size_t)k * 25 + c * 3 + 1] = cy[c];
        out[(size_t)k * 25 + c * 3 + 2] = cz[c];
        mnx = fminf(mnx, cx[c]); mny = fminf(mny, cy[c]);
        mxx = fmaxf(mxx, cx[c]); mxy = fmaxf(mxy, cy[c]);
    }
    stand[k] = make_float4(mnx, mny, mxx, mxy);
}

// ---------------- K5: suppression bitmask (4 rows per 256-thr block) --------
__global__ void __launch_bounds__(256) k_mask(const float4* __restrict__ stand,
                                              u64* __restrict__ mask) {
    int i = blockIdx.x * 4 + (threadIdx.x >> 6);
    int t = threadIdx.x & 63;
    int w0 = i >> 6;                    // chunks below diagonal are all-zero
    float4 bi = stand[i];
    float areai = (bi.z - bi.x) * (bi.w - bi.y);
    u64 myword = 0ull;
    for (int w = w0; w < 64; ++w) {
        int j = w * 64 + t;
        float4 bj = stand[j];
        float areaj = (bj.z - bj.x) * (bj.w - bj.y);
        float ltx = fmaxf(bi.x, bj.x), lty = fmaxf(bi.y, bj.y);
        float rbx = fminf(bi.z, bj.z), rby = fminf(bi.w, bj.w);
        float iw = fmaxf(rbx - ltx, 0.0f), ih = fmaxf(rby - lty, 0.0f);
        float inter = iw * ih;
        float iou = inter / (areai + areaj - inter + 1e-6f);
        bool sup = (iou > NMS_THR) && (j > i);
        u64 bits = __ballot(sup);
        if (t == w) myword = bits;
    }
    mask[(size_t)i * 64 + t] = myword;
}

// ---------------- K6: 4-wave cooperative greedy NMS (scalar chain + dbuf) ---
__device__ __forceinline__ void nms_step(int B, u64 (&rcur)[16], u64 (&rnxt)[16],
                                         const u64* __restrict__ mask,
                                         const float* __restrict__ sc,
                                         u64& colB, float& mysc,
                                         u64* remv_sh, u64* keep_sh, u64* kb_sh,
                                         int w, int l) {
    if (B + 1 < 64) {   // prefetch next chunk's rows (chain-independent)
        const u64* rp = mask + (size_t)((B + 1) * 64 + w * 16) * 64 + l;
#pragma unroll
        for (int k2 = 0; k2 < 16; ++k2) rnxt[k2] = rp[(size_t)k2 * 64];
    }
    u64 colB_next = 0ull;
    float sc_next = 0.0f;
    if (w == 0) {
        if (B + 1 < 64) {
            colB_next = mask[(size_t)((B + 1) * 64 + l) * 64 + (B + 1)];
            sc_next   = sc[(B + 1) * 64 + l];
        }
        u64 validm = __ballot(mysc > SCORE_THR);            // SGPR
        u64 c0 = remv_sh[B];
        u64 curw = (((u64)(u32)__builtin_amdgcn_readfirstlane((int)(u32)(c0 >> 32))) << 32)
                 |  ((u64)(u32)__builtin_amdgcn_readfirstlane((int)(u32)c0));
        u32 clo = (u32)colB, chi = (u32)(colB >> 32);
        u64 alive = validm & ~curw;                          // SGPR chain
        u64 kb = 0ull;
        while (alive) {
            int r = (int)__builtin_ctzll(alive);             // s_ff1
            u64 col_r = (((u64)(u32)__builtin_amdgcn_readlane((int)chi, r)) << 32)
                      |   (u64)(u32)__builtin_amdgcn_readlane((int)clo, r);
            kb |= 1ull << r;
            alive &= ~(col_r | (1ull << r));
        }
        if (l == 0) { *kb_sh = kb; keep_sh[B] = kb; }
    }
    __syncthreads();     // kb visible; remv_sh[B] read precedes fold writes
    u64 kb = *kb_sh;
    u64 p = 0ull;
#pragma unroll
    for (int k2 = 0; k2 < 16; ++k2)
        p |= rcur[k2] & (0ull - ((kb >> (w * 16 + k2)) & 1ull));
    if (p) atomicOr(&remv_sh[l], p);
    __syncthreads();     // fold(B) complete before chain reads remv_sh[B+1]
    colB = colB_next;
    mysc = sc_next;
}

__global__ void __launch_bounds__(256) k_nms(const u64* __restrict__ mask,
                                             const float* __restrict__ sc,
                                             float* __restrict__ out) {
    __shared__ u64 remv_sh[64];
    __shared__ u64 keep_sh[64];
    __shared__ u64 kb_sh;
    int tid = threadIdx.x;
    int w = tid >> 6, l = tid & 63;
    if (tid < 64) remv_sh[tid] = 0ull;
    u64 bufA[16], bufB[16];
    {   // preload chunk 0 rows
        const u64* rp = mask + (size_t)(w * 16) * 64 + l;
#pragma unroll
        for (int k2 = 0; k2 < 16; ++k2) bufA[k2] = rp[(size_t)k2 * 64];
    }
    u64 colB = 0ull;
    float mysc = 0.0f;
    if (w == 0) { colB = mask[(size_t)l * 64]; mysc = sc[l]; }
    __syncthreads();
    for (int B = 0; B < 64; B += 2) {
        nms_step(B,     bufA, bufB, mask, sc, colB, mysc, remv_sh, keep_sh, &kb_sh, w, l);
        nms_step(B + 1, bufB, bufA, mask, sc, colB, mysc, remv_sh, keep_sh, &kb_sh, w, l);
    }
#pragma unroll
    for (int j = 0; j < 16; ++j) {
        int i = tid * 16 + j;
        float s = sc[i];
        out[(size_t)i * 25 + 24] = ((keep_sh[i >> 6] >> (i & 63)) & 1ull) ? s : 0.0f;
    }
}

extern "C" void kernel_launch(void* const* d_in, const int* in_sizes, int n_in,
                              void* d_out, int out_size, void* d_ws, size_t ws_size,
                              hipStream_t stream) {
    const float* anchors = (const float*)d_in[0];
    const float* psm_v   = (const float*)d_in[1];
    const float* rm_v    = (const float*)d_in[2];
    const float* psm_i   = (const float*)d_in[3];
    const float* rm_i    = (const float*)d_in[4];
    const float* tproj   = (const float*)d_in[5];
    const float* tego    = (const float*)d_in[6];
    float* out = (float*)d_out;
    char* ws = (char*)d_ws;

    u32*    keys    = (u32*)(ws + OFF_KEYS);
    u64*    mask    = (u64*)(ws + OFF_KEYS);    // reuse after keys consumed
    u32*    ghist   = (u32*)(ws + OFF_GHIST);
    u64*    cand    = (u64*)(ws + OFF_CAND);
    float4* stand   = (float4*)(ws + OFF_STAND);
    u32*    cnt     = (u32*)(ws + OFF_CNT);
    u32*    sel_idx = (u32*)(ws + OFF_SELIDX);
    float*  sel_sc  = (float*)(ws + OFF_SELSC);

    hipMemsetAsync(ws + OFF_GHIST, 0, 4096, stream);
    k_keys   <<<NT / 1024, 1024, 0, stream>>>(psm_v, psm_i, keys, ghist);
    k_select <<<1, 1024, 0, stream>>>(ghist, keys, cand, cnt);
    k_rank   <<<32, 256, 0, stream>>>(cand, cnt, sel_idx);
    k_boxes  <<<TOPK / 256, 256, 0, stream>>>(anchors, psm_v, psm_i, rm_v, rm_i,
                                              tproj, tego, sel_idx, sel_sc, out, stand);
    k_mask   <<<TOPK / 4, 256, 0, stream>>>(stand, mask);
    k_nms    <<<1, 256, 0, stream>>>(mask, sel_sc, out);
}

// Round 10
// 383.476 us; speedup vs baseline: 2.1691x; 1.0999x over previous
//
#include <hip/hip_runtime.h>
#include <stdint.h>

typedef unsigned int u32;
typedef unsigned long long u64;

#define HH 256
#define WW 512
#define HW (HH*WW)          // 131072
#define N2 (2*HW)           // 262144 per branch
#define NT (2*N2)           // 524288 total boxes
#define TOPK 4096
#define SCORE_THR 0.2f
#define NMS_THR 0.15f

// ---- workspace layout (bytes) ----
// [0, 2MB)  keys -> reused as NMS mask (4096*64 u64 = 2 MB exactly)
#define OFF_KEYS   0ull
#define OFF_GHIST  ((size_t)NT*4)                  // u32[1024] = 4 KB @ 2,097,152
#define OFF_GHIST2 (OFF_GHIST + 4096)              // u32[1024] = 4 KB
#define OFF_CNT    (OFF_GHIST2 + 4096)             // u32 (+pad 16)
#define OFF_VALIDM (OFF_CNT + 16)                  // u64[64] = 512 B
#define OFF_CAND   (OFF_VALIDM + 512)              // u64[8192] = 64 KB
#define OFF_STAND  OFF_CAND                        // float4[4096] = 64 KB (cand dead
                                                   //  after k_rank; stand born in k_boxes)
#define OFF_SELIDX (OFF_CAND + 65536)              // u32[4096]
#define OFF_SELSC  (OFF_SELIDX + (size_t)TOPK*4)   // f32[4096]
// end ~2,204,176 B < 2,261,008 proven in R6/R8
#define ZERO_BYTES (4096 + 4096 + 16)              // ghist + ghist2 + cnt

// orderable key for float (descending sortable as unsigned)
__device__ __forceinline__ u32 f2ord(float f) {
    u32 b = __float_as_uint(f);
    return (b & 0x80000000u) ? ~b : (b | 0x80000000u);
}

// ---------------- K1: scores -> keys + per-block LDS hist1 -> global -------
__global__ void __launch_bounds__(1024) k_keys(const float* __restrict__ psm_v,
                                               const float* __restrict__ psm_i,
                                               u32* __restrict__ keys,
                                               u32* __restrict__ ghist) {
    __shared__ u32 lh[1024];
    int t = threadIdx.x;
    lh[t] = 0;
    __syncthreads();
    int n = blockIdx.x * 1024 + t;
    int br = n >> 18;
    int m  = n & (N2 - 1);
    int a  = m & 1;
    int hw = m >> 1;
    const float* psm = br ? psm_i : psm_v;
    float x = psm[a * HW + hw];
    float s = 1.0f / (1.0f + __builtin_expf(-x));   // mirror ref f32 sigmoid
    u32 key = 0u;
    if (s > SCORE_THR) key = f2ord(s);
    keys[n] = key;
    if (key) atomicAdd(&lh[key >> 22], 1u);
    __syncthreads();
    u32 c = lh[t];
    if (c) atomicAdd(&ghist[t], c);
}

// Wave-0 suffix-scan pivot over a 1024-entry count array (16 entries/lane).
// suffix(b) non-increasing -> unique crossing (lane,j) writes result (race-free).
__device__ __forceinline__ void pivot1024(const u32* __restrict__ arr, u32 target,
                                          u32* out_bin, u32* out_next, int l) {
    u32 h[16], loc[16];
#pragma unroll
    for (int j = 0; j < 16; ++j) h[j] = arr[l * 16 + j];
    loc[15] = h[15];
#pragma unroll
    for (int j = 14; j >= 0; --j) loc[j] = loc[j + 1] + h[j];
    u32 T = loc[0];
    u32 incl = T;
#pragma unroll
    for (int d = 1; d < 64; d <<= 1) {
        u32 v = __shfl_down(incl, d);
        if (l + d < 64) incl += v;
    }
    u32 E = incl - T;                      // sum over lanes > l
#pragma unroll
    for (int j = 0; j < 16; ++j) {
        u32 S  = loc[j] + E;
        u32 Sn = (j < 15 ? loc[j + 1] : 0u) + E;
        if (S >= target && Sn < target) {
            *out_bin = (u32)(l * 16 + j);
            *out_next = Sn;
        }
    }
}

// ---------------- K2: hist2 over key>>12 within pivot-1 bin (512 blocks) ----
// Each block re-derives pivot1 from ghist in wave 0 (deterministic), then
// LDS-aggregated histogram -> global ghist2. R1-proven structure.
__global__ void __launch_bounds__(1024) k_hist2(const u32* __restrict__ ghist,
                                                const u32* __restrict__ keys,
                                                u32* __restrict__ ghist2) {
    __shared__ u32 lh[1024];
    __shared__ u32 b1_sh;
    int tid = threadIdx.x;
    lh[tid] = 0;
    if (tid < 64) {
        u32 bin = 0xFFFFFFFFu, nxt = 0;
        pivot1024(ghist, (u32)TOPK, &bin, &nxt, tid);
        if (bin != 0xFFFFFFFFu) b1_sh = bin;    // winner-lane writes
    }
    __syncthreads();
    u32 b1 = b1_sh;
    int n = blockIdx.x * 1024 + tid;
    u32 key = keys[n];
    if ((key >> 22) == b1) atomicAdd(&lh[(key >> 12) & 1023u], 1u);
    __syncthreads();
    u32 c = lh[tid];
    if (c) atomicAdd(&ghist2[tid], c);
}

// ---------------- K3: compact at 20-bit cut (512 blocks) --------------------
// Re-derives both pivots, then R1-proven global-atomic compaction.
__global__ void __launch_bounds__(1024) k_collect(const u32* __restrict__ ghist,
                                                  const u32* __restrict__ ghist2,
                                                  const u32* __restrict__ keys,
                                                  u64* __restrict__ cand,
                                                  u32* __restrict__ cnt) {
    __shared__ u32 b1_sh, t2_sh, b2_sh;
    int tid = threadIdx.x;
    if (tid < 64) {
        u32 bin = 0xFFFFFFFFu, nxt = 0;
        pivot1024(ghist, (u32)TOPK, &bin, &nxt, tid);
        if (bin != 0xFFFFFFFFu) { b1_sh = bin; t2_sh = (u32)TOPK - nxt; }
    }
    __syncthreads();
    if (tid < 64) {
        u32 bin = 0xFFFFFFFFu, nxt = 0;
        pivot1024(ghist2, t2_sh, &bin, &nxt, tid);
        if (bin != 0xFFFFFFFFu) b2_sh = bin;
    }
    __syncthreads();
    u32 thr20 = (b1_sh << 10) | b2_sh;
    int n = blockIdx.x * 1024 + tid;
    u32 key = keys[n];
    if ((key >> 12) >= thr20) {
        u32 pos = atomicAdd(cnt, 1u);
        if (pos < 8192u)
            cand[pos] = ((u64)key << 32) | (u64)(u32)(~(u32)n);
    }
}

// ---------------- K4: rank-by-counting selection ----------------------------
__global__ void __launch_bounds__(256) k_rank(const u64* __restrict__ cand,
                                              const u32* __restrict__ cnt,
                                              u32* __restrict__ sel_idx) {
    __shared__ u64 tile[1024];
    int tid = threadIdx.x;
    int i = blockIdx.x * 256 + tid;
    u32 c = *cnt;
    if (c > 8192u) c = 8192u;
    u64 my = (i < (int)c) ? cand[i] : 0ull;
    u32 rank = 0;
    for (u32 base = 0; base < c; base += 1024) {
#pragma unroll
        for (int k = 0; k < 4; ++k) {
            u32 idx = base + tid + k * 256;
            tile[tid + k * 256] = (idx < c) ? cand[idx] : 0ull;
        }
        __syncthreads();
        u32 lim = (c - base < 1024u) ? (c - base) : 1024u;
#pragma unroll 4
        for (u32 k = 0; k < lim; ++k) rank += (tile[k] > my) ? 1u : 0u;
        __syncthreads();
    }
    if (i < (int)c && rank < (u32)TOPK)
        sel_idx[rank] = ~((u32)(my & 0xFFFFFFFFull));
}

// ---------------- box math helpers (mirror the jax reference) ---------------
__device__ __forceinline__ void box_corners(const float b[7], float cx[8], float cy[8], float cz[8]) {
    const float sx[8] = {0.5f,0.5f,-0.5f,-0.5f,0.5f,0.5f,-0.5f,-0.5f};
    const float sy[8] = {0.5f,-0.5f,-0.5f,0.5f,0.5f,-0.5f,-0.5f,0.5f};
    const float sz[8] = {-0.5f,-0.5f,-0.5f,-0.5f,0.5f,0.5f,0.5f,0.5f};
    float c = __builtin_cosf(b[6]), s = __builtin_sinf(b[6]);
#pragma unroll
    for (int k = 0; k < 8; k++) {
        float x = b[5] * sx[k], y = b[4] * sy[k], z = b[3] * sz[k];
        cx[k] = x * c - y * s + b[0];
        cy[k] = x * s + y * c + b[1];
        cz[k] = z + b[2];
    }
}

__device__ __forceinline__ void proj_T(const float* __restrict__ T, float cx[8], float cy[8], float cz[8]) {
#pragma unroll
    for (int k = 0; k < 8; k++) {
        float x = cx[k], y = cy[k], z = cz[k];
        cx[k] = T[0] * x + T[1] * y + T[2]  * z + T[3];
        cy[k] = T[4] * x + T[5] * y + T[6]  * z + T[7];
        cz[k] = T[8] * x + T[9] * y + T[10] * z + T[11];
    }
}

__device__ __forceinline__ void corner_to_center(const float cx[8], const float cy[8], const float cz[8], float b[7]) {
    float mx = 0.f, my = 0.f, mz = 0.f;
#pragma unroll
    for (int k = 0; k < 8; k++) { mx += cx[k]; my += cy[k]; mz += cz[k]; }
    mx *= 0.125f; my *= 0.125f; mz *= 0.125f;
    float htop = (cz[4] + cz[5] + cz[6] + cz[7]) * 0.25f;
    float hbot = (cz[0] + cz[1] + cz[2] + cz[3]) * 0.25f;
    const int lA[4] = {0,1,4,5}, lB[4] = {3,2,7,6};
    const int wA[4] = {0,3,4,7}, wB[4] = {1,2,5,6};
    float l = 0.f, w = 0.f, dx = 0.f, dy = 0.f;
#pragma unroll
    for (int i = 0; i < 4; i++) {
        float ax = cx[lA[i]] - cx[lB[i]];
        float ay = cy[lA[i]] - cy[lB[i]];
        l += __builtin_sqrtf(ax * ax + ay * ay);
        dx += ax; dy += ay;
    }
#pragma unroll
    for (int i = 0; i < 4; i++) {
        float ax = cx[wA[i]] - cx[wB[i]];
        float ay = cy[wA[i]] - cy[wB[i]];
        w += __builtin_sqrtf(ax * ax + ay * ay);
    }
    b[0] = mx; b[1] = my; b[2] = mz;
    b[3] = htop - hbot;
    b[4] = w * 0.25f;
    b[5] = l * 0.25f;
    b[6] = atan2f(dy, dx);
}

// ---------------- K5: decode boxes -> out corners + standup + validm --------
__global__ void __launch_bounds__(256) k_boxes(const float* __restrict__ anchors,
                                               const float* __restrict__ psm_v,
                                               const float* __restrict__ psm_i,
                                               const float* __restrict__ rm_v,
                                               const float* __restrict__ rm_i,
                                               const float* __restrict__ tproj,
                                               const float* __restrict__ tego,
                                               const u32* __restrict__ sel_idx,
                                               float* __restrict__ sel_sc,
                                               float* __restrict__ out,
                                               float4* __restrict__ stand,
                                               u64* __restrict__ validm) {
    int k = blockIdx.x * blockDim.x + threadIdx.x;
    if (k >= TOPK) return;
    int n = (int)(sel_idx[k] & (u32)(NT - 1));
    int br = n >> 18;
    int m  = n & (N2 - 1);
    int a  = m & 1;
    int hw = m >> 1;

    const float* psm = br ? psm_i : psm_v;
    float xs = psm[a * HW + hw];
    float s  = 1.0f / (1.0f + __builtin_expf(-xs));
    sel_sc[k] = (s > SCORE_THR) ? s : -1.0f;
    u64 vbits = __ballot(s > SCORE_THR);
    if ((threadIdx.x & 63) == 0) validm[k >> 6] = vbits;   // one word per wave

    const float* rm = br ? rm_i : rm_v;
    float d[7];
#pragma unroll
    for (int j = 0; j < 7; j++) d[j] = rm[(a * 7 + j) * HW + hw];
    const float* anc = anchors + (size_t)m * 7;
    float a0 = anc[0], a1 = anc[1], a2 = anc[2], a3 = anc[3], a4 = anc[4], a5 = anc[5], a6 = anc[6];
    float ad = __builtin_sqrtf(a4 * a4 + a5 * a5);
    float b[7];
    b[0] = d[0] * ad + a0;
    b[1] = d[1] * ad + a1;
    b[2] = d[2] * a3 + a2;
    b[3] = __builtin_expf(d[3]) * a3;
    b[4] = __builtin_expf(d[4]) * a4;
    b[5] = __builtin_expf(d[5]) * a5;
    b[6] = d[6] + a6;

    if (br) {  // infrared branch: corners -> t_proj -> back to center form
        float cx[8], cy[8], cz[8];
        box_corners(b, cx, cy, cz);
        proj_T(tproj, cx, cy, cz);
        corner_to_center(cx, cy, cz, b);
    }

    float cx[8], cy[8], cz[8];
    box_corners(b, cx, cy, cz);
    proj_T(tego, cx, cy, cz);

    float mnx = cx[0], mny = cy[0], mxx = cx[0], mxy = cy[0];
#pragma unroll
    for (int c = 0; c < 8; c++) {
        out[(size_t)k * 25 + c * 3 + 0] = cx[c];
        out[(size_t)k * 25 + c * 3 + 1] = cy[c];
        out[(size_t)k * 25 + c * 3 + 2] = cz[c];
        mnx = fminf(mnx, cx[c]); mny = fminf(mny, cy[c]);
        mxx = fmaxf(mxx, cx[c]); mxy = fmaxf(mxy, cy[c]);
    }
    stand[k] = make_float4(mnx, mny, mxx, mxy);
}

// ---------------- K6: suppression bitmask (4 rows per 256-thr block) --------
__global__ void __launch_bounds__(256) k_mask(const float4* __restrict__ stand,
                                              u64* __restrict__ mask) {
    int i = blockIdx.x * 4 + (threadIdx.x >> 6);
    int t = threadIdx.x & 63;
    int w0 = i >> 6;                    // chunks below diagonal are all-zero
    float4 bi = stand[i];
    float areai = (bi.z - bi.x) * (bi.w - bi.y);
    u64 myword = 0ull;
    for (int w = w0; w < 64; ++w) {
        int j = w * 64 + t;
        float4 bj = stand[j];
        float areaj = (bj.z - bj.x) * (bj.w - bj.y);
        float ltx = fmaxf(bi.x, bj.x), lty = fmaxf(bi.y, bj.y);
        float rbx = fminf(bi.z, bj.z), rby = fminf(bi.w, bj.w);
        float iw = fmaxf(rbx - ltx, 0.0f), ih = fmaxf(rby - lty, 0.0f);
        float inter = iw * ih;
        float iou = inter / (areai + areaj - inter + 1e-6f);
        bool sup = (iou > NMS_THR) && (j > i);
        u64 bits = __ballot(sup);
        if (t == w) myword = bits;
    }
    mask[(size_t)i * 64 + t] = myword;
}

// ---------------- K7: single-wave greedy NMS, LDS double-buffer via DMA -----
// Zero barriers, zero cross-wave sync. global_load_lds is a side-effect op the
// compiler CANNOT sink to use (unlike register loads of read-only data, which
// it rematerialized in R3/R7/R9 — VGPR_Count proved it). Chunk B+1's 32 KB is
// DMA'd into the ping-pong half while chunk B's scalar chain runs; one
// s_waitcnt vmcnt(0) per chunk (single-wave: no deadlock modes). The chunk's
// intra-chunk column word colB is read from the staged buffer itself.
__global__ void __launch_bounds__(64) k_nms(const u64* __restrict__ mask,
                                            const u64* __restrict__ validm,
                                            const float* __restrict__ sc,
                                            float* __restrict__ out) {
    __shared__ u64 buf[2][4096];   // 64 KB (k_sort proved 64 KB static LDS ok)
    int l = threadIdx.x;
    u64 remv = 0ull;   // lane l: suppression word l
    u64 keep = 0ull;   // lane l: keep word of chunk l
    // prologue: stage chunk 0 into buf[0]
#pragma unroll
    for (int j = 0; j < 32; ++j) {
        const u64* g = mask + (size_t)j * 128 + l * 2;      // 2 rows per call
        __builtin_amdgcn_global_load_lds(
            (const __attribute__((address_space(1))) void*)g,
            (__attribute__((address_space(3))) void*)&buf[0][j * 128], 16, 0, 0);
    }
    __builtin_amdgcn_s_waitcnt(0x0F70);   // vmcnt(0)
    asm volatile("" ::: "memory");
    for (int B = 0; B < 64; ++B) {
        int cur = B & 1;
        // stage chunk B+1 into the other half (in flight during the chain)
        if (B < 63) {
            const u64* gb = mask + (size_t)(B + 1) * 4096;
#pragma unroll
            for (int j = 0; j < 32; ++j) {
                const u64* g = gb + (size_t)j * 128 + l * 2;
                __builtin_amdgcn_global_load_lds(
                    (const __attribute__((address_space(1))) void*)g,
                    (__attribute__((address_space(3))) void*)&buf[cur ^ 1][j * 128],
                    16, 0, 0);
            }
        }
        // chain inputs: colB from staged chunk (lane l = row l's word B),
        // validm[B] uniform load, curw = remv word B via readlane
        u64 colB = buf[cur][l * 64 + B];
        u64 vm = validm[B];
        u64 curw = (((u64)(u32)__builtin_amdgcn_readlane((int)(u32)(remv >> 32), B)) << 32)
                 |   (u64)(u32)__builtin_amdgcn_readlane((int)(u32)remv, B);
        u32 clo = (u32)colB, chi = (u32)(colB >> 32);
        u64 alive = vm & ~curw;
        u64 kb = 0ull;
        while (alive) {                       // wave-uniform scalar chain
            int r = (int)__builtin_ctzll(alive);
            u64 col_r = (((u64)(u32)__builtin_amdgcn_readlane((int)chi, r)) << 32)
                      |   (u64)(u32)__builtin_amdgcn_readlane((int)clo, r);
            kb |= 1ull << r;
            alive &= ~(col_r | (1ull << r));
        }
        keep = (l == B) ? kb : keep;
        // drain the B+1 DMAs (had ~chain-duration in flight), then fold chunk B
        __builtin_amdgcn_s_waitcnt(0x0F70);   // vmcnt(0)
        asm volatile("" ::: "memory");
        u64 p = 0ull;
#pragma unroll
        for (int r = 0; r < 64; ++r)
            p |= buf[cur][r * 64 + l] & (0ull - ((kb >> r) & 1ull));
        remv |= p;
    }
    // epilogue: lane l writes final-score column of chunk l
    for (int r = 0; r < 64; ++r) {
        int i = l * 64 + r;
        float s = sc[i];
        out[(size_t)i * 25 + 24] = ((keep >> r) & 1ull) ? s : 0.0f;
    }
}

extern "C" void kernel_launch(void* const* d_in, const int* in_sizes, int n_in,
                              void* d_out, int out_size, void* d_ws, size_t ws_size,
                              hipStream_t stream) {
    const float* anchors = (const float*)d_in[0];
    const float* psm_v   = (const float*)d_in[1];
    const float* rm_v    = (const float*)d_in[2];
    const float* psm_i   = (const float*)d_in[3];
    const float* rm_i    = (const float*)d_in[4];
    const float* tproj   = (const float*)d_in[5];
    const float* tego    = (const float*)d_in[6];
    float* out = (float*)d_out;
    char* ws = (char*)d_ws;

    u32*    keys    = (u32*)(ws + OFF_KEYS);
    u64*    mask    = (u64*)(ws + OFF_KEYS);    // reuse after keys consumed
    u32*    ghist   = (u32*)(ws + OFF_GHIST);
    u32*    ghist2  = (u32*)(ws + OFF_GHIST2);
    u32*    cnt     = (u32*)(ws + OFF_CNT);
    u64*    validm  = (u64*)(ws + OFF_VALIDM);
    u64*    cand    = (u64*)(ws + OFF_CAND);
    float4* stand   = (float4*)(ws + OFF_STAND);   // overlays cand (sequential-safe)
    u32*    sel_idx = (u32*)(ws + OFF_SELIDX);
    float*  sel_sc  = (float*)(ws + OFF_SELSC);

    hipMemsetAsync(ws + OFF_GHIST, 0, ZERO_BYTES, stream);
    k_keys   <<<NT / 1024, 1024, 0, stream>>>(psm_v, psm_i, keys, ghist);
    k_hist2  <<<NT / 1024, 1024, 0, stream>>>(ghist, keys, ghist2);
    k_collect<<<NT / 1024, 1024, 0, stream>>>(ghist, ghist2, keys, cand, cnt);
    k_rank   <<<32, 256, 0, stream>>>(cand, cnt, sel_idx);
    k_boxes  <<<TOPK / 256, 256, 0, stream>>>(anchors, psm_v, psm_i, rm_v, rm_i,
                                              tproj, tego, sel_idx, sel_sc, out,
                                              stand, validm);
    k_mask   <<<TOPK / 4, 256, 0, stream>>>(stand, mask);
    k_nms    <<<1, 64, 0, stream>>>(mask, validm, sel_sc, out);
}

// Round 11
// 335.842 us; speedup vs baseline: 2.4768x; 1.1418x over previous
//
#include <hip/hip_runtime.h>
#include <stdint.h>

typedef unsigned int u32;
typedef unsigned long long u64;

#define HH 256
#define WW 512
#define HW (HH*WW)          // 131072
#define N2 (2*HW)           // 262144 per branch
#define NT (2*N2)           // 524288 total boxes
#define TOPK 4096
#define SCORE_THR 0.2f
#define NMS_THR 0.15f

// ---- workspace layout (bytes) ----
// [0, 2MB)  keys -> reused as NMS mask (4096*64 u64 = 2 MB exactly)
#define OFF_KEYS   0ull
#define OFF_GHIST  ((size_t)NT*4)                  // u32[1024] = 4 KB @ 2,097,152
#define OFF_GHIST2 (OFF_GHIST + 4096)              // u32[1024] = 4 KB
#define OFF_CNT    (OFF_GHIST2 + 4096)             // u32 (+pad 16)
#define OFF_VALIDM (OFF_CNT + 16)                  // u64[64] = 512 B
#define OFF_CAND   (OFF_VALIDM + 512)              // u64[8192] = 64 KB
#define OFF_STAND  OFF_CAND                        // float4[4096] overlays cand
#define OFF_SELIDX (OFF_CAND + 65536)              // u32[4096]
#define OFF_SELSC  (OFF_SELIDX + (size_t)TOPK*4)   // f32[4096]
#define OFF_TDIAG  (OFF_SELSC + (size_t)TOPK*4)    // u64[4096] = 32 KB @ 2,204,176
// end = 2,236,944 B < 2,261,008 proven in R6/R8
#define ZERO_BYTES (4096 + 4096 + 16)              // ghist + ghist2 + cnt

// orderable key for float (descending sortable as unsigned)
__device__ __forceinline__ u32 f2ord(float f) {
    u32 b = __float_as_uint(f);
    return (b & 0x80000000u) ? ~b : (b | 0x80000000u);
}

// ---------------- K1: scores -> keys + per-block LDS hist1 -> global -------
__global__ void __launch_bounds__(1024) k_keys(const float* __restrict__ psm_v,
                                               const float* __restrict__ psm_i,
                                               u32* __restrict__ keys,
                                               u32* __restrict__ ghist) {
    __shared__ u32 lh[1024];
    int t = threadIdx.x;
    lh[t] = 0;
    __syncthreads();
    int n = blockIdx.x * 1024 + t;
    int br = n >> 18;
    int m  = n & (N2 - 1);
    int a  = m & 1;
    int hw = m >> 1;
    const float* psm = br ? psm_i : psm_v;
    float x = psm[a * HW + hw];
    float s = 1.0f / (1.0f + __builtin_expf(-x));   // mirror ref f32 sigmoid
    u32 key = 0u;
    if (s > SCORE_THR) key = f2ord(s);
    keys[n] = key;
    if (key) atomicAdd(&lh[key >> 22], 1u);
    __syncthreads();
    u32 c = lh[t];
    if (c) atomicAdd(&ghist[t], c);
}

// Wave-0 suffix-scan pivot over a 1024-entry count array (16 entries/lane).
// suffix(b) non-increasing -> unique crossing (lane,j) writes result (race-free).
__device__ __forceinline__ void pivot1024(const u32* __restrict__ arr, u32 target,
                                          u32* out_bin, u32* out_next, int l) {
    u32 h[16], loc[16];
#pragma unroll
    for (int j = 0; j < 16; ++j) h[j] = arr[l * 16 + j];
    loc[15] = h[15];
#pragma unroll
    for (int j = 14; j >= 0; --j) loc[j] = loc[j + 1] + h[j];
    u32 T = loc[0];
    u32 incl = T;
#pragma unroll
    for (int d = 1; d < 64; d <<= 1) {
        u32 v = __shfl_down(incl, d);
        if (l + d < 64) incl += v;
    }
    u32 E = incl - T;                      // sum over lanes > l
#pragma unroll
    for (int j = 0; j < 16; ++j) {
        u32 S  = loc[j] + E;
        u32 Sn = (j < 15 ? loc[j + 1] : 0u) + E;
        if (S >= target && Sn < target) {
            *out_bin = (u32)(l * 16 + j);
            *out_next = Sn;
        }
    }
}

// ---------------- K2: hist2 over key>>12 within pivot-1 bin (512 blocks) ----
__global__ void __launch_bounds__(1024) k_hist2(const u32* __restrict__ ghist,
                                                const u32* __restrict__ keys,
                                                u32* __restrict__ ghist2) {
    __shared__ u32 lh[1024];
    __shared__ u32 b1_sh;
    int tid = threadIdx.x;
    lh[tid] = 0;
    if (tid < 64) {
        u32 bin = 0xFFFFFFFFu, nxt = 0;
        pivot1024(ghist, (u32)TOPK, &bin, &nxt, tid);
        if (bin != 0xFFFFFFFFu) b1_sh = bin;    // winner-lane writes
    }
    __syncthreads();
    u32 b1 = b1_sh;
    int n = blockIdx.x * 1024 + tid;
    u32 key = keys[n];
    if ((key >> 22) == b1) atomicAdd(&lh[(key >> 12) & 1023u], 1u);
    __syncthreads();
    u32 c = lh[tid];
    if (c) atomicAdd(&ghist2[tid], c);
}

// ---------------- K3: compact at 20-bit cut (512 blocks) --------------------
__global__ void __launch_bounds__(1024) k_collect(const u32* __restrict__ ghist,
                                                  const u32* __restrict__ ghist2,
                                                  const u32* __restrict__ keys,
                                                  u64* __restrict__ cand,
                                                  u32* __restrict__ cnt) {
    __shared__ u32 b1_sh, t2_sh, b2_sh;
    int tid = threadIdx.x;
    if (tid < 64) {
        u32 bin = 0xFFFFFFFFu, nxt = 0;
        pivot1024(ghist, (u32)TOPK, &bin, &nxt, tid);
        if (bin != 0xFFFFFFFFu) { b1_sh = bin; t2_sh = (u32)TOPK - nxt; }
    }
    __syncthreads();
    if (tid < 64) {
        u32 bin = 0xFFFFFFFFu, nxt = 0;
        pivot1024(ghist2, t2_sh, &bin, &nxt, tid);
        if (bin != 0xFFFFFFFFu) b2_sh = bin;
    }
    __syncthreads();
    u32 thr20 = (b1_sh << 10) | b2_sh;
    int n = blockIdx.x * 1024 + tid;
    u32 key = keys[n];
    if ((key >> 12) >= thr20) {
        u32 pos = atomicAdd(cnt, 1u);
        if (pos < 8192u)
            cand[pos] = ((u64)key << 32) | (u64)(u32)(~(u32)n);
    }
}

// ---------------- K4: rank-by-counting selection ----------------------------
__global__ void __launch_bounds__(256) k_rank(const u64* __restrict__ cand,
                                              const u32* __restrict__ cnt,
                                              u32* __restrict__ sel_idx) {
    __shared__ u64 tile[1024];
    int tid = threadIdx.x;
    int i = blockIdx.x * 256 + tid;
    u32 c = *cnt;
    if (c > 8192u) c = 8192u;
    u64 my = (i < (int)c) ? cand[i] : 0ull;
    u32 rank = 0;
    for (u32 base = 0; base < c; base += 1024) {
#pragma unroll
        for (int k = 0; k < 4; ++k) {
            u32 idx = base + tid + k * 256;
            tile[tid + k * 256] = (idx < c) ? cand[idx] : 0ull;
        }
        __syncthreads();
        u32 lim = (c - base < 1024u) ? (c - base) : 1024u;
#pragma unroll 4
        for (u32 k = 0; k < lim; ++k) rank += (tile[k] > my) ? 1u : 0u;
        __syncthreads();
    }
    if (i < (int)c && rank < (u32)TOPK)
        sel_idx[rank] = ~((u32)(my & 0xFFFFFFFFull));
}

// ---------------- box math helpers (mirror the jax reference) ---------------
__device__ __forceinline__ void box_corners(const float b[7], float cx[8], float cy[8], float cz[8]) {
    const float sx[8] = {0.5f,0.5f,-0.5f,-0.5f,0.5f,0.5f,-0.5f,-0.5f};
    const float sy[8] = {0.5f,-0.5f,-0.5f,0.5f,0.5f,-0.5f,-0.5f,0.5f};
    const float sz[8] = {-0.5f,-0.5f,-0.5f,-0.5f,0.5f,0.5f,0.5f,0.5f};
    float c = __builtin_cosf(b[6]), s = __builtin_sinf(b[6]);
#pragma unroll
    for (int k = 0; k < 8; k++) {
        float x = b[5] * sx[k], y = b[4] * sy[k], z = b[3] * sz[k];
        cx[k] = x * c - y * s + b[0];
        cy[k] = x * s + y * c + b[1];
        cz[k] = z + b[2];
    }
}

__device__ __forceinline__ void proj_T(const float* __restrict__ T, float cx[8], float cy[8], float cz[8]) {
#pragma unroll
    for (int k = 0; k < 8; k++) {
        float x = cx[k], y = cy[k], z = cz[k];
        cx[k] = T[0] * x + T[1] * y + T[2]  * z + T[3];
        cy[k] = T[4] * x + T[5] * y + T[6]  * z + T[7];
        cz[k] = T[8] * x + T[9] * y + T[10] * z + T[11];
    }
}

__device__ __forceinline__ void corner_to_center(const float cx[8], const float cy[8], const float cz[8], float b[7]) {
    float mx = 0.f, my = 0.f, mz = 0.f;
#pragma unroll
    for (int k = 0; k < 8; k++) { mx += cx[k]; my += cy[k]; mz += cz[k]; }
    mx *= 0.125f; my *= 0.125f; mz *= 0.125f;
    float htop = (cz[4] + cz[5] + cz[6] + cz[7]) * 0.25f;
    float hbot = (cz[0] + cz[1] + cz[2] + cz[3]) * 0.25f;
    const int lA[4] = {0,1,4,5}, lB[4] = {3,2,7,6};
    const int wA[4] = {0,3,4,7}, wB[4] = {1,2,5,6};
    float l = 0.f, w = 0.f, dx = 0.f, dy = 0.f;
#pragma unroll
    for (int i = 0; i < 4; i++) {
        float ax = cx[lA[i]] - cx[lB[i]];
        float ay = cy[lA[i]] - cy[lB[i]];
        l += __builtin_sqrtf(ax * ax + ay * ay);
        dx += ax; dy += ay;
    }
#pragma unroll
    for (int i = 0; i < 4; i++) {
        float ax = cx[wA[i]] - cx[wB[i]];
        float ay = cy[wA[i]] - cy[wB[i]];
        w += __builtin_sqrtf(ax * ax + ay * ay);
    }
    b[0] = mx; b[1] = my; b[2] = mz;
    b[3] = htop - hbot;
    b[4] = w * 0.25f;
    b[5] = l * 0.25f;
    b[6] = atan2f(dy, dx);
}

// ---------------- K5: decode boxes -> out corners + standup + validm --------
__global__ void __launch_bounds__(256) k_boxes(const float* __restrict__ anchors,
                                               const float* __restrict__ psm_v,
                                               const float* __restrict__ psm_i,
                                               const float* __restrict__ rm_v,
                                               const float* __restrict__ rm_i,
                                               const float* __restrict__ tproj,
                                               const float* __restrict__ tego,
                                               const u32* __restrict__ sel_idx,
                                               float* __restrict__ sel_sc,
                                               float* __restrict__ out,
                                               float4* __restrict__ stand,
                                               u64* __restrict__ validm) {
    int k = blockIdx.x * blockDim.x + threadIdx.x;
    if (k >= TOPK) return;
    int n = (int)(sel_idx[k] & (u32)(NT - 1));
    int br = n >> 18;
    int m  = n & (N2 - 1);
    int a  = m & 1;
    int hw = m >> 1;

    const float* psm = br ? psm_i : psm_v;
    float xs = psm[a * HW + hw];
    float s  = 1.0f / (1.0f + __builtin_expf(-xs));
    sel_sc[k] = (s > SCORE_THR) ? s : -1.0f;
    u64 vbits = __ballot(s > SCORE_THR);
    if ((threadIdx.x & 63) == 0) validm[k >> 6] = vbits;   // one word per wave

    const float* rm = br ? rm_i : rm_v;
    float d[7];
#pragma unroll
    for (int j = 0; j < 7; j++) d[j] = rm[(a * 7 + j) * HW + hw];
    const float* anc = anchors + (size_t)m * 7;
    float a0 = anc[0], a1 = anc[1], a2 = anc[2], a3 = anc[3], a4 = anc[4], a5 = anc[5], a6 = anc[6];
    float ad = __builtin_sqrtf(a4 * a4 + a5 * a5);
    float b[7];
    b[0] = d[0] * ad + a0;
    b[1] = d[1] * ad + a1;
    b[2] = d[2] * a3 + a2;
    b[3] = __builtin_expf(d[3]) * a3;
    b[4] = __builtin_expf(d[4]) * a4;
    b[5] = __builtin_expf(d[5]) * a5;
    b[6] = d[6] + a6;

    if (br) {  // infrared branch: corners -> t_proj -> back to center form
        float cx[8], cy[8], cz[8];
        box_corners(b, cx, cy, cz);
        proj_T(tproj, cx, cy, cz);
        corner_to_center(cx, cy, cz, b);
    }

    float cx[8], cy[8], cz[8];
    box_corners(b, cx, cy, cz);
    proj_T(tego, cx, cy, cz);

    float mnx = cx[0], mny = cy[0], mxx = cx[0], mxy = cy[0];
#pragma unroll
    for (int c = 0; c < 8; c++) {
        out[(size_t)k * 25 + c * 3 + 0] = cx[c];
        out[(size_t)k * 25 + c * 3 + 1] = cy[c];
        out[(size_t)k * 25 + c * 3 + 2] = cz[c];
        mnx = fminf(mnx, cx[c]); mny = fminf(mny, cy[c]);
        mxx = fmaxf(mxx, cx[c]); mxy = fmaxf(mxy, cy[c]);
    }
    stand[k] = make_float4(mnx, mny, mxx, mxy);
}

// ---------------- K6: suppression bitmask (4 rows per 256-thr block) --------
__global__ void __launch_bounds__(256) k_mask(const float4* __restrict__ stand,
                                              u64* __restrict__ mask) {
    int i = blockIdx.x * 4 + (threadIdx.x >> 6);
    int t = threadIdx.x & 63;
    int w0 = i >> 6;                    // chunks below diagonal are all-zero
    float4 bi = stand[i];
    float areai = (bi.z - bi.x) * (bi.w - bi.y);
    u64 myword = 0ull;
    for (int w = w0; w < 64; ++w) {
        int j = w * 64 + t;
        float4 bj = stand[j];
        float areaj = (bj.z - bj.x) * (bj.w - bj.y);
        float ltx = fmaxf(bi.x, bj.x), lty = fmaxf(bi.y, bj.y);
        float rbx = fminf(bi.z, bj.z), rby = fminf(bi.w, bj.w);
        float iw = fmaxf(rbx - ltx, 0.0f), ih = fmaxf(rby - lty, 0.0f);
        float inter = iw * ih;
        float iou = inter / (areai + areaj - inter + 1e-6f);
        bool sup = (iou > NMS_THR) && (j > i);
        u64 bits = __ballot(sup);
        if (t == w) myword = bits;
    }
    mask[(size_t)i * 64 + t] = myword;
}

// ---------------- K7: transposed intra-chunk suppression words --------------
// Block B, lane l: Tdiag bit j = "chunk-B box j suppresses chunk-B box l"
// = j < l && iou(j,l) > thr. IoU math identical to k_mask (fp add commutes,
// min/max symmetric -> bit-identical decisions).
__global__ void __launch_bounds__(64) k_diag(const float4* __restrict__ stand,
                                             u64* __restrict__ tdiag) {
    __shared__ float4 sb[64];
    int B = blockIdx.x, l = threadIdx.x;
    float4 me = stand[B * 64 + l];
    sb[l] = me;
    __syncthreads();
    float aream = (me.z - me.x) * (me.w - me.y);
    u64 T = 0ull;
    for (int j = 0; j < 64; ++j) {
        float4 bj = sb[j];                       // suppressor candidate
        float areaj = (bj.z - bj.x) * (bj.w - bj.y);
        float ltx = fmaxf(bj.x, me.x), lty = fmaxf(bj.y, me.y);
        float rbx = fminf(bj.z, me.z), rby = fminf(bj.w, me.w);
        float iw = fmaxf(rbx - ltx, 0.0f), ih = fmaxf(rby - lty, 0.0f);
        float inter = iw * ih;
        float iou = inter / (areaj + aream - inter + 1e-6f);
        bool sup = (iou > NMS_THR) && (j < l);
        T |= sup ? (1ull << j) : 0ull;
    }
    tdiag[B * 64 + l] = T;
}

// ---------------- K8: single-wave greedy NMS, fixpoint chain + DMA dbuf -----
// Chain: monotone two-mask fixpoint (D grows, P shrinks, converges to the
// exact greedy keep set — lowest-bit-of-P\D argument) using precomputed
// transposed words Tl. ~2 ballots/iter, ~3-6 iters/chunk: no per-box serial
// readlane chain. DMA: chunk B+1 staged via global_load_lds while chunk B's
// chain+fold run; the vmcnt(0) drain sits at loop END (fold reads only
// buf[cur], resident since the previous iteration).
__global__ void __launch_bounds__(64) k_nms(const u64* __restrict__ mask,
                                            const u64* __restrict__ tdiag,
                                            const u64* __restrict__ validm,
                                            const float* __restrict__ sc,
                                            float* __restrict__ out) {
    __shared__ u64 buf[2][4096];   // 64 KB ping-pong
    int l = threadIdx.x;
    u64 remv = 0ull;   // lane l: suppression word l
    u64 keep = 0ull;   // lane l: keep word of chunk l
    // prologue: stage chunk 0 into buf[0]
#pragma unroll
    for (int j = 0; j < 32; ++j) {
        const u64* g = mask + (size_t)j * 128 + l * 2;      // 1 KB per call
        __builtin_amdgcn_global_load_lds(
            (const __attribute__((address_space(1))) void*)g,
            (__attribute__((address_space(3))) void*)&buf[0][j * 128], 16, 0, 0);
    }
    __builtin_amdgcn_s_waitcnt(0x0F70);   // vmcnt(0)
    asm volatile("" ::: "memory");
    for (int B = 0; B < 64; ++B) {
        int cur = B & 1;
        // issue chunk B+1's staging (in flight during chain+fold)
        if (B < 63) {
            const u64* gb = mask + (size_t)(B + 1) * 4096;
#pragma unroll
            for (int j = 0; j < 32; ++j) {
                const u64* g = gb + (size_t)j * 128 + l * 2;
                __builtin_amdgcn_global_load_lds(
                    (const __attribute__((address_space(1))) void*)g,
                    (__attribute__((address_space(3))) void*)&buf[cur ^ 1][j * 128],
                    16, 0, 0);
            }
        }
        // ---- chain (no LDS, no serial readlane loop) ----
        u64 Tl = tdiag[B * 64 + l];
        u64 vm = validm[B];
        u64 curw = (((u64)(u32)__builtin_amdgcn_readlane((int)(u32)(remv >> 32), B)) << 32)
                 |   (u64)(u32)__builtin_amdgcn_readlane((int)(u32)remv, B);
        u64 ve = vm & ~curw;               // eligible within chunk
        u64 D = 0ull, P = ve;              // definite (grows) / possible (shrinks)
        while (D != P) {                   // wave-uniform; exact greedy at fixpoint
            u64 nD = ve & ~__ballot((Tl & P) != 0ull);
            u64 nP = ve & ~__ballot((Tl & nD) != 0ull);
            D = nD; P = nP;
        }
        u64 kb = D;
        keep = (l == B) ? kb : keep;
        // ---- fold chunk B's kept rows from resident buf[cur] ----
        u64 p = 0ull;
#pragma unroll
        for (int r = 0; r < 64; ++r)
            p |= buf[cur][r * 64 + l] & (0ull - ((kb >> r) & 1ull));
        remv |= p;
        // ---- drain chunk B+1 (had chain+fold duration to complete) ----
        if (B < 63) {
            __builtin_amdgcn_s_waitcnt(0x0F70);   // vmcnt(0)
            asm volatile("" ::: "memory");
        }
    }
    // epilogue: lane l writes final-score column of chunk l
    for (int r = 0; r < 64; ++r) {
        int i = l * 64 + r;
        float s = sc[i];
        out[(size_t)i * 25 + 24] = ((keep >> r) & 1ull) ? s : 0.0f;
    }
}

extern "C" void kernel_launch(void* const* d_in, const int* in_sizes, int n_in,
                              void* d_out, int out_size, void* d_ws, size_t ws_size,
                              hipStream_t stream) {
    const float* anchors = (const float*)d_in[0];
    const float* psm_v   = (const float*)d_in[1];
    const float* rm_v    = (const float*)d_in[2];
    const float* psm_i   = (const float*)d_in[3];
    const float* rm_i    = (const float*)d_in[4];
    const float* tproj   = (const float*)d_in[5];
    const float* tego    = (const float*)d_in[6];
    float* out = (float*)d_out;
    char* ws = (char*)d_ws;

    u32*    keys    = (u32*)(ws + OFF_KEYS);
    u64*    mask    = (u64*)(ws + OFF_KEYS);    // reuse after keys consumed
    u32*    ghist   = (u32*)(ws + OFF_GHIST);
    u32*    ghist2  = (u32*)(ws + OFF_GHIST2);
    u32*    cnt     = (u32*)(ws + OFF_CNT);
    u64*    validm  = (u64*)(ws + OFF_VALIDM);
    u64*    cand    = (u64*)(ws + OFF_CAND);
    float4* stand   = (float4*)(ws + OFF_STAND);   // overlays cand (sequential-safe)
    u32*    sel_idx = (u32*)(ws + OFF_SELIDX);
    float*  sel_sc  = (float*)(ws + OFF_SELSC);
    u64*    tdiag   = (u64*)(ws + OFF_TDIAG);

    hipMemsetAsync(ws + OFF_GHIST, 0, ZERO_BYTES, stream);
    k_keys   <<<NT / 1024, 1024, 0, stream>>>(psm_v, psm_i, keys, ghist);
    k_hist2  <<<NT / 1024, 1024, 0, stream>>>(ghist, keys, ghist2);
    k_collect<<<NT / 1024, 1024, 0, stream>>>(ghist, ghist2, keys, cand, cnt);
    k_rank   <<<32, 256, 0, stream>>>(cand, cnt, sel_idx);
    k_boxes  <<<TOPK / 256, 256, 0, stream>>>(anchors, psm_v, psm_i, rm_v, rm_i,
                                              tproj, tego, sel_idx, sel_sc, out,
                                              stand, validm);
    k_mask   <<<TOPK / 4, 256, 0, stream>>>(stand, mask);
    k_diag   <<<64, 64, 0, stream>>>(stand, tdiag);
    k_nms    <<<1, 64, 0, stream>>>(mask, tdiag, validm, sel_sc, out);
}